// Round 20
// baseline (190.223 us; speedup 1.0000x reference)
//
#include <hip/hip_runtime.h>
#include <hip/hip_bf16.h>

typedef __hip_bfloat16 bf16;
typedef short bf16x8 __attribute__((ext_vector_type(8)));
typedef float f32x4 __attribute__((ext_vector_type(4)));

#define HT 16384   // bf16 half-tile bytes: 128 rows x 64 cols

__device__ __forceinline__ void gload16(const void* g, void* l) {
    __builtin_amdgcn_global_load_lds(
        (const __attribute__((address_space(1))) void*)g,
        (__attribute__((address_space(3))) void*)l, 16, 0, 0);
}

// 512-thread staging of one 128x64 half-tile (2 gload16/thread)
__device__ __forceinline__ void stage_half(char* lds, const bf16* src, int ld,
                                           int rowbase, int k0, int slotIdx,
                                           int tid)
{
    char* dst = lds + (size_t)slotIdx * HT + tid * 16;
    const int sub = tid >> 3;
    const int cb  = ((tid & 7) ^ (sub & 7)) << 4;
    #pragma unroll
    for (int p = 0; p < 2; ++p) {
        const int row = p * 64 + sub;
        const char* g = (const char*)(src + (size_t)(rowbase + row) * ld + k0) + cb;
        gload16(g, dst + p * 8192);
    }
}

// 256-thread staging of one 128x64 half-tile (4 gload16/thread)
__device__ __forceinline__ void stage_q(char* lds, const bf16* src, int ld,
                                        int rowbase, int k0, int slotIdx,
                                        int tid)
{
    char* dst = lds + (size_t)slotIdx * HT + tid * 16;
    #pragma unroll
    for (int p = 0; p < 4; ++p) {
        const int s = p * 256 + tid;
        const int row = s >> 3;
        const int cb = ((s & 7) ^ (row & 7)) << 4;
        const char* g = (const char*)(src + (size_t)(rowbase + row) * ld + k0) + cb;
        gload16(g, dst + p * 4096);
    }
}

// read one MFMA A/B fragment (8 bf16 = 16B) with the read-side swizzle
__device__ __forceinline__ bf16x8 ldsfrag(const char* lds, int slotIdx,
                                          int row, int ks, int cb0)
{
    return *(const bf16x8*)(lds + (size_t)slotIdx * HT
                            + row * 128 + (cb0 ^ (ks << 6)));
}

__device__ __forceinline__ float bf2f(short s) {
    union { float f; unsigned u; } c;
    c.u = ((unsigned)(unsigned short)s) << 16;
    return c.f;
}

// ====== core 256x128 K=1024 loop body (8 waves 4Mx2N, 128 KiB LDS) ======
#define MF8(n0)                                                               \
    _Pragma("unroll") for (int m = 0; m < 4; ++m)                             \
    _Pragma("unroll") for (int dn = 0; dn < 2; ++dn)                          \
    _Pragma("unroll") for (int ks = 0; ks < 2; ++ks)                          \
        acc[m][(n0)+dn] = __builtin_amdgcn_mfma_f32_16x16x32_bf16(            \
            af[m][ks], bv[(n0)+dn][ks], acc[m][(n0)+dn], 0, 0, 0);

#define GEMM256_BODY(A_, lda_, B_, ldb_, brow_, bcol_)                        \
    f32x4 acc[4][4] = {};                                                     \
    bf16x8 af[4][2], bv[4][2];                                                \
    stage_half(lds, A_, lda_, brow_,       0, 0, tid);                        \
    stage_half(lds, A_, lda_, brow_ + 128, 0, 1, tid);                        \
    stage_half(lds, B_, ldb_, bcol_,       0, 6, tid);                        \
    stage_half(lds, A_, lda_, brow_,      64, 2, tid);                        \
    stage_half(lds, A_, lda_, brow_ + 128,64, 3, tid);                        \
    stage_half(lds, B_, ldb_, bcol_,     64, 7, tid);                         \
    asm volatile("s_waitcnt vmcnt(6)" ::: "memory");                          \
    __builtin_amdgcn_s_barrier();                                             \
    for (int t = 0; t < 16; ++t) {                                            \
        const int aslot = (t % 3) * 2 + hA;                                   \
        const int bslot = 6 + (t & 1);                                        \
        const int a2    = ((t + 2) % 3) * 2;                                  \
        const int k2    = min(t + 2, 15) << 6;                                \
        _Pragma("unroll") for (int m = 0; m < 4; ++m)                         \
        _Pragma("unroll") for (int ks = 0; ks < 2; ++ks)                      \
            af[m][ks] = ldsfrag(lds, aslot, rA + m * 16 + fr, ks, cb0);       \
        _Pragma("unroll") for (int n = 0; n < 4; ++n)                         \
        _Pragma("unroll") for (int ks = 0; ks < 2; ++ks)                      \
            bv[n][ks] = ldsfrag(lds, bslot, rB + n * 16 + fr, ks, cb0);       \
        stage_half(lds, A_, lda_, brow_,       k2, a2,     tid);              \
        stage_half(lds, A_, lda_, brow_ + 128, k2, a2 + 1, tid);              \
        __builtin_amdgcn_s_barrier();                                         \
        __builtin_amdgcn_s_setprio(1);                                        \
        MF8(0)                                                                \
        __builtin_amdgcn_s_setprio(0);                                        \
        __builtin_amdgcn_s_barrier();                                         \
        stage_half(lds, B_, ldb_, bcol_, k2, bslot, tid);                     \
        __builtin_amdgcn_s_barrier();                                         \
        __builtin_amdgcn_s_setprio(1);                                        \
        MF8(2)                                                                \
        __builtin_amdgcn_s_setprio(0);                                        \
        asm volatile("s_waitcnt vmcnt(6)" ::: "memory");                      \
        __builtin_amdgcn_s_barrier();                                         \
    }

// generic K=1024 GEMM: MODE 0: Cb = bf16(A@B^T).  MODE 2: Cf = f32(A@B^T).
template<int MODE>
__launch_bounds__(512, 2)
__global__ void gemm_a256(const bf16* __restrict__ A, const bf16* __restrict__ B,
                          bf16* __restrict__ Cb, float* __restrict__ Cf)
{
    extern __shared__ char lds[];
    const int gx = gridDim.x;
    const int nwg = gx * gridDim.y;
    const int chunk = nwg >> 3;
    const int orig = blockIdx.y * gx + blockIdx.x;
    const int wk2 = (orig & 7) * chunk + (orig >> 3);
    const int bi = wk2 / gx, bj = wk2 % gx;
    const int brow = bi * 256, bcol = bj * 128;

    const int tid  = threadIdx.x;
    const int lane = tid & 63;
    const int w    = tid >> 6;
    const int wm   = w >> 1, wn = w & 1;               // 4M x 2N, wave 64x64
    const int fr   = lane & 15, fq = lane >> 4;
    const int cb0  = ((fr & 7) ^ fq) << 4;
    const int hA   = wm >> 1;
    const int rA   = (wm & 1) * 64;
    const int rB   = wn * 64;

    GEMM256_BODY(A, 1024, B, 1024, brow, bcol)

    #pragma unroll
    for (int mf = 0; mf < 4; ++mf) {
        const int r0 = brow + wm * 64 + mf * 16 + fq * 4;
        #pragma unroll
        for (int nf = 0; nf < 4; ++nf) {
            const int c = bcol + wn * 64 + nf * 16 + fr;
            #pragma unroll
            for (int j = 0; j < 4; ++j) {
                if (MODE == 0)
                    Cb[(size_t)(r0 + j) * 1024 + c] =
                        __float2bfloat16(acc[mf][nf][j]);
                else
                    Cf[(size_t)(r0 + j) * 1024 + c] = acc[mf][nf][j];
            }
        }
    }
}

// ====== scores, 8-phase 256x256 template (m201 schedule; R13-proven) ======
__launch_bounds__(512, 1)
__global__ void scores8(const bf16* __restrict__ qG, const bf16* __restrict__ kb,
                        bf16* __restrict__ P)
{
    extern __shared__ char lds[];
    const int orig = blockIdx.y * 8 + blockIdx.x;     // grid (8,18) = 144
    const int wk2 = (orig & 7) * 18 + (orig >> 3);    // bijective, 18/XCD
    const int bz = wk2 / 36;
    const int j  = wk2 % 36;
    int bi = (int)((__fsqrt_rn(8.0f * j + 1.0f) - 1.0f) * 0.5f);
    while ((bi + 1) * (bi + 2) / 2 <= j) ++bi;
    while (bi * (bi + 1) / 2 > j) --bi;
    const int bj = j - bi * (bi + 1) / 2;             // bj <= bi
    const int brow = bi * 256, bcol = bj * 256;
    const bf16* A = qG + (size_t)bz * 2048 * 1024;
    const bf16* B = kb + (size_t)bz * 2048 * 1024;
    bf16* Cp = P + (size_t)bz * 2048 * 2048;

    const int tid  = threadIdx.x;
    const int lane = tid & 63;
    const int w    = tid >> 6;
    const int wm   = w >> 2;              // A half this wave owns (0..1)
    const int wn   = w & 3;               // B 64-col group (0..3)
    const int bh   = wn >> 1;             // B half slot
    const int rBl  = (wn & 1) * 64;       // local row base in B half
    const int fr   = lane & 15, fq = lane >> 4;
    const int cb0  = ((fr & 7) ^ fq) << 4;

    f32x4 acc[8][4] = {};
    bf16x8 af0[4][2], af1[4][2], bv0[2][2], bv1[2][2];

#define AS(t,h) ((((t) % 3) * 2) + (h))
#define BS(t,h) (6 + (((t) & 1) * 2) + (h))

    stage_half(lds, A, 1024, brow,       0, AS(0,0), tid);
    stage_half(lds, A, 1024, brow + 128, 0, AS(0,1), tid);
    stage_half(lds, B, 1024, bcol,       0, BS(0,0), tid);
    stage_half(lds, B, 1024, bcol + 128, 0, BS(0,1), tid);
    stage_half(lds, A, 1024, brow,      64, AS(1,0), tid);
    stage_half(lds, A, 1024, brow + 128,64, AS(1,1), tid);
    stage_half(lds, B, 1024, bcol,     64, BS(1,0), tid);
    asm volatile("s_waitcnt vmcnt(6)" ::: "memory");
    __builtin_amdgcn_s_barrier();

#define MFQ(MH, NH, AF, BV)                                                   \
    _Pragma("unroll") for (int m = 0; m < 4; ++m)                             \
    _Pragma("unroll") for (int n = 0; n < 2; ++n)                             \
    _Pragma("unroll") for (int ks = 0; ks < 2; ++ks)                          \
        acc[(MH)*4+m][(NH)*2+n] = __builtin_amdgcn_mfma_f32_16x16x32_bf16(    \
            AF[m][ks], BV[n][ks], acc[(MH)*4+m][(NH)*2+n], 0, 0, 0);

    for (int t = 0; t < 16; ++t) {
        const int kN  = min(t + 1, 15) << 6;
        const int kNN = min(t + 2, 15) << 6;
        const int as  = AS(t, wm);
        const int bs2 = BS(t, bh);

        // ph0: quadrant (0,0); stage B1(t+1)
        #pragma unroll
        for (int m = 0; m < 4; ++m)
            #pragma unroll
            for (int ks = 0; ks < 2; ++ks)
                af0[m][ks] = ldsfrag(lds, as, m * 16 + fr, ks, cb0);
        #pragma unroll
        for (int n = 0; n < 2; ++n)
            #pragma unroll
            for (int ks = 0; ks < 2; ++ks)
                bv0[n][ks] = ldsfrag(lds, bs2, rBl + n * 16 + fr, ks, cb0);
        stage_half(lds, B, 1024, bcol + 128, kN, BS(t + 1, 1), tid);
        __builtin_amdgcn_s_barrier();
        __builtin_amdgcn_s_setprio(1);
        MFQ(0, 0, af0, bv0)
        __builtin_amdgcn_s_setprio(0);
        __builtin_amdgcn_s_barrier();

        // ph1: quadrant (1,0); stage A0(t+2)
        #pragma unroll
        for (int m = 0; m < 4; ++m)
            #pragma unroll
            for (int ks = 0; ks < 2; ++ks)
                af1[m][ks] = ldsfrag(lds, as, 64 + m * 16 + fr, ks, cb0);
        stage_half(lds, A, 1024, brow, kNN, AS(t + 2, 0), tid);
        __builtin_amdgcn_s_barrier();
        __builtin_amdgcn_s_setprio(1);
        MFQ(1, 0, af1, bv0)
        __builtin_amdgcn_s_setprio(0);
        __builtin_amdgcn_s_barrier();

        // ph2: quadrant (1,1); stage A1(t+2)
        #pragma unroll
        for (int n = 0; n < 2; ++n)
            #pragma unroll
            for (int ks = 0; ks < 2; ++ks)
                bv1[n][ks] = ldsfrag(lds, bs2, rBl + 32 + n * 16 + fr, ks, cb0);
        stage_half(lds, A, 1024, brow + 128, kNN, AS(t + 2, 1), tid);
        __builtin_amdgcn_s_barrier();
        __builtin_amdgcn_s_setprio(1);
        MFQ(1, 1, af1, bv1)
        __builtin_amdgcn_s_setprio(0);
        __builtin_amdgcn_s_barrier();

        // ph3: quadrant (0,1); stage B0(t+2); counted vmcnt(6)
        stage_half(lds, B, 1024, bcol, kNN, BS(t + 2, 0), tid);
        __builtin_amdgcn_s_barrier();
        __builtin_amdgcn_s_setprio(1);
        MFQ(0, 1, af0, bv1)
        __builtin_amdgcn_s_setprio(0);
        asm volatile("s_waitcnt vmcnt(6)" ::: "memory");
        __builtin_amdgcn_s_barrier();
    }
#undef MFQ
#undef AS
#undef BS

    #pragma unroll
    for (int mf = 0; mf < 8; ++mf) {
        const int r0 = brow + wm * 128 + mf * 16 + fq * 4;
        #pragma unroll
        for (int nf = 0; nf < 4; ++nf) {
            const int c = bcol + wn * 64 + nf * 16 + fr;
            #pragma unroll
            for (int jj = 0; jj < 4; ++jj)
                Cp[(size_t)(r0 + jj) * 2048 + c] =
                    __float2bfloat16(acc[mf][nf][jj] * 0.03125f);
        }
    }
}

// ====== PV engine: 256 thr, 4 waves 2Mx2N, block 128x128, 80 KiB ======
__device__ __forceinline__ void tile128pv(char* lds, const bf16* A, const bf16* B,
                                          bf16* Cb, const bf16* Res,
                                          int lda, int ldb, int ldcb,
                                          int brow, int bcol, int NT, int tid)
{
    const int lane = tid & 63;
    const int w    = tid >> 6;
    const int wm   = w >> 1, wn = w & 1;
    const int fr   = lane & 15, fq = lane >> 4;
    const int cb0  = ((fr & 7) ^ fq) << 4;

    f32x4 acc[4][4] = {};
    bf16x8 af[4][2], bv[4][2];

    stage_q(lds, A, lda, brow, 0,  0, tid);
    stage_q(lds, B, ldb, bcol, 0,  3, tid);
    stage_q(lds, A, lda, brow, 64, 1, tid);
    stage_q(lds, B, ldb, bcol, 64, 4, tid);
    asm volatile("s_waitcnt vmcnt(8)" ::: "memory");
    __builtin_amdgcn_s_barrier();

    for (int t = 0; t < NT; ++t) {
        const int aslot = t % 3, bslot = 3 + (t & 1);
        const int k2 = min(t + 2, NT - 1) << 6;

        #pragma unroll
        for (int m = 0; m < 4; ++m)
            #pragma unroll
            for (int ks = 0; ks < 2; ++ks)
                af[m][ks] = ldsfrag(lds, aslot, wm * 64 + m * 16 + fr, ks, cb0);
        #pragma unroll
        for (int n = 0; n < 4; ++n)
            #pragma unroll
            for (int ks = 0; ks < 2; ++ks)
                bv[n][ks] = ldsfrag(lds, bslot, wn * 64 + n * 16 + fr, ks, cb0);
        stage_q(lds, A, lda, brow, k2, (t + 2) % 3, tid);
        __builtin_amdgcn_s_barrier();
        __builtin_amdgcn_s_setprio(1);
        #pragma unroll
        for (int m = 0; m < 4; ++m)
            #pragma unroll
            for (int n = 0; n < 2; ++n)
                #pragma unroll
                for (int ks = 0; ks < 2; ++ks)
                    acc[m][n] = __builtin_amdgcn_mfma_f32_16x16x32_bf16(
                        af[m][ks], bv[n][ks], acc[m][n], 0, 0, 0);
        __builtin_amdgcn_s_setprio(0);
        __builtin_amdgcn_s_barrier();

        stage_q(lds, B, ldb, bcol, k2, bslot, tid);
        __builtin_amdgcn_s_barrier();
        __builtin_amdgcn_s_setprio(1);
        #pragma unroll
        for (int m = 0; m < 4; ++m)
            #pragma unroll
            for (int n = 2; n < 4; ++n)
                #pragma unroll
                for (int ks = 0; ks < 2; ++ks)
                    acc[m][n] = __builtin_amdgcn_mfma_f32_16x16x32_bf16(
                        af[m][ks], bv[n][ks], acc[m][n], 0, 0, 0);
        __builtin_amdgcn_s_setprio(0);
        asm volatile("s_waitcnt vmcnt(8)" ::: "memory");
        __builtin_amdgcn_s_barrier();
    }

    #pragma unroll
    for (int mf = 0; mf < 4; ++mf) {
        const int r0 = brow + wm * 64 + mf * 16 + fq * 4;
        #pragma unroll
        for (int nf = 0; nf < 4; ++nf) {
            const int c = bcol + wn * 64 + nf * 16 + fr;
            #pragma unroll
            for (int j = 0; j < 4; ++j)
                Cb[(size_t)(r0 + j) * ldcb + c] = __float2bfloat16(
                    acc[mf][nf][j] +
                    __bfloat162float(Res[(size_t)(r0 + j) * ldcb + c]));
        }
    }
}

// PV: Y = attn@v + qb (bf16 residual). 512 balanced single tiles.
__launch_bounds__(256, 2)
__global__ void pv128(const bf16* __restrict__ P, const bf16* __restrict__ vT,
                      const bf16* __restrict__ qb, bf16* __restrict__ Y)
{
    extern __shared__ char lds[];
    const int x  = blockIdx.x;                // 0..511
    const int u  = x & 255;
    const int bs = u & 7;
    const int bj = (u >> 3) & 7;
    const int bz = u >> 6;
    const int bi = (x >> 8) ? (15 - bs) : bs;

    tile128pv(lds,
              P + (size_t)bz * 2048 * 2048,
              vT + (size_t)bz * 1024 * 2048,
              Y + (size_t)bz * 2048 * 1024,
              qb + (size_t)bz * 2048 * 1024,
              2048, 2048, 1024,
              bi * 128, bj * 128, 2 * (bi + 1), threadIdx.x);
}

// ====== convert: q,k,wi -> qb,kb,Wb (pure streaming) ======
__global__ void convert_qkw(const float* __restrict__ q, const float* __restrict__ k,
                            const float* __restrict__ wi,
                            bf16* __restrict__ qb, bf16* __restrict__ kb,
                            bf16* __restrict__ Wb)
{
    const int N8 = 8192 * 1024 / 8, W8 = 1024 * 1024 / 8;
    const int total = 2 * N8 + W8;
    for (int i = blockIdx.x * 256 + threadIdx.x; i < total; i += gridDim.x * 256) {
        const float4* s;
        bf16* dst;
        int j;
        if (i < N8)          { s = (const float4*)q;  dst = qb; j = i; }
        else if (i < 2 * N8) { s = (const float4*)k;  dst = kb; j = i - N8; }
        else                 { s = (const float4*)wi; dst = Wb; j = i - 2 * N8; }
        float4 a = s[2 * j], bb = s[2 * j + 1];
        float vals[8] = {a.x, a.y, a.z, a.w, bb.x, bb.y, bb.z, bb.w};
        union { short h[8]; bf16x8 v8; } o;
        #pragma unroll
        for (int e = 0; e < 8; ++e) {
            bf16 hh = __float2bfloat16(vals[e]);
            o.h[e] = *(short*)&hh;
        }
        ((bf16x8*)dst)[j] = o.v8;
    }
}

// ====== 256x256 macro transpose: 1KB load rows AND 512B store segments ======
// LDS 128 KiB, swizzle chunk ^= s&31 keeps both phases bank-bounded.
// Grid 144 blocks (128 v-tiles + 16 wi-tiles) = one round at 1 block/CU.
__launch_bounds__(512, 1)
__global__ void transpose_vwi(const float* __restrict__ v,
                              const float* __restrict__ wi,
                              bf16* __restrict__ vT, bf16* __restrict__ Wt)
{
    extern __shared__ char lds[];
    bf16* tl = (bf16*)lds;
    const int idx = blockIdx.x;
    const int tid = threadIdx.x;

    const float* src;
    bf16* dst;
    int ldsrc, lddst, r0, c0;
    if (idx < 128) {            // vT[z][d][s] = bf16(v[z][s][d])
        const int z = idx >> 5, rem = idx & 31;
        src = v + (size_t)z * 2048 * 1024; ldsrc = 1024;
        dst = vT + (size_t)z * 1024 * 2048; lddst = 2048;
        r0 = (rem >> 2) * 256;            // s base (load rows)
        c0 = (rem & 3) * 256;             // d base (load cols)
    } else {                    // Wt[n][k] = bf16(wi[k][n])
        const int t2 = idx - 128;
        src = wi; ldsrc = 1024; dst = Wt; lddst = 1024;
        r0 = (t2 >> 2) * 256;             // k base
        c0 = (t2 & 3) * 256;              // n base
    }

    // load: 256 rows x 256 f32 (1KB per row, 64 consecutive lanes per row)
    #pragma unroll 4
    for (int p = 0; p < 32; ++p) {
        const int fid = p * 512 + tid;
        const int s  = fid >> 6;          // 0..255
        const int c4 = fid & 63;          // float4 index within row
        const int d0 = c4 * 4;
        float4 x = *(const float4*)(src + (size_t)(r0 + s) * ldsrc + c0 + d0);
        bf16 h0 = __float2bfloat16(x.x), h1 = __float2bfloat16(x.y),
             h2 = __float2bfloat16(x.z), h3 = __float2bfloat16(x.w);
        union { short h[4]; short4 v4; } o;
        o.h[0] = *(short*)&h0; o.h[1] = *(short*)&h1;
        o.h[2] = *(short*)&h2; o.h[3] = *(short*)&h3;
        char* a = (char*)tl + s * 512 + (((d0 >> 3) ^ (s & 31)) << 4)
                  + (d0 & 7) * 2;         // 8B-aligned (d0&7 in {0,4})
        *(short4*)a = o.v4;
    }
    __syncthreads();

    // store: 256 d-rows x 256 s (512B contiguous per d-row; 32 lanes/row)
    #pragma unroll 4
    for (int p = 0; p < 16; ++p) {
        const int d  = p * 16 + (tid >> 5);
        const int s0 = (tid & 31) * 8;
        union { short h[8]; bf16x8 v8; } o;
        #pragma unroll
        for (int j = 0; j < 8; ++j) {
            const int s = s0 + j;
            const char* a = (const char*)tl + s * 512
                            + (((d >> 3) ^ (s & 31)) << 4) + (d & 7) * 2;
            o.h[j] = *(const short*)a;
        }
        *(bf16x8*)(dst + (size_t)(c0 + d) * lddst + r0 + s0) = o.v8;
    }
}

// wave-per-row causal softmax, zero-fill to 128-aligned boundary
__launch_bounds__(256)
__global__ void softmax_rows(bf16* __restrict__ P)
{
    const int wid = threadIdx.x >> 6, lane = threadIdx.x & 63;
    const int r = blockIdx.x * 4 + wid, b = blockIdx.y;
    bf16* row = P + ((size_t)b * 2048 + r) * 2048;
    const int nv  = r + 1;
    const int rup = (r & ~127) + 128;

    float vals[4][8];
    float m = -1e30f;
    #pragma unroll
    for (int c = 0; c < 4; ++c) {
        const int k0 = c * 512 + lane * 8;
        if (k0 < rup) {
            bf16x8 x = *(const bf16x8*)(row + k0);
            #pragma unroll
            for (int j = 0; j < 8; ++j) {
                float f = (k0 + j < nv) ? bf2f(x[j]) : -1e30f;
                vals[c][j] = f;
                m = fmaxf(m, f);
            }
        } else {
            #pragma unroll
            for (int j = 0; j < 8; ++j) vals[c][j] = -1e30f;
        }
    }
    #pragma unroll
    for (int o = 32; o; o >>= 1) m = fmaxf(m, __shfl_xor(m, o));

    float sum = 0.f;
    #pragma unroll
    for (int c = 0; c < 4; ++c)
        #pragma unroll
        for (int j = 0; j < 8; ++j) {
            float e = __expf(vals[c][j] - m);
            vals[c][j] = e;
            sum += e;
        }
    #pragma unroll
    for (int o = 32; o; o >>= 1) sum += __shfl_xor(sum, o);
    const float inv = 1.0f / sum;

    #pragma unroll
    for (int c = 0; c < 4; ++c) {
        const int k0 = c * 512 + lane * 8;
        if (k0 < rup) {
            union { short h[8]; bf16x8 v8; } o;
            #pragma unroll
            for (int j = 0; j < 8; ++j) {
                bf16 hh = __float2bfloat16(vals[c][j] * inv);
                o.h[j] = *(short*)&hh;
            }
            *(bf16x8*)(row + k0) = o.v8;
        }
    }
}

extern "C" void kernel_launch(void* const* d_in, const int* in_sizes, int n_in,
                              void* d_out, int out_size, void* d_ws, size_t ws_size,
                              hipStream_t stream)
{
    const float* v  = (const float*)d_in[0];
    const float* k  = (const float*)d_in[1];
    const float* q  = (const float*)d_in[2];
    const float* wi = (const float*)d_in[3];
    float* out = (float*)d_out;

    char* ws = (char*)d_ws;
    const size_t MB = 1u << 20;
    bf16* Wb = (bf16*)(ws);                 // [1024][1024] W row-major
    bf16* Wt = (bf16*)(ws + 2 * MB);        // [1024][1024] W^T
    bf16* G  = (bf16*)(ws + 4 * MB);        // [1024][1024] W@W^T
    bf16* qb = (bf16*)(ws + 6 * MB);        // [8192][1024]
    bf16* kb = (bf16*)(ws + 22 * MB);       // [8192][1024]
    bf16* vT = (bf16*)(ws + 38 * MB);       // [4][1024][2048]
    bf16* qG = (bf16*)(ws + 54 * MB);       // [8192][1024]
    bf16* Y  = (bf16*)(ws + 70 * MB);       // [8192][1024]  q + attn@v
    bf16* P  = (bf16*)(ws + 86 * MB);       // [4][2048][2048]

    (void)hipFuncSetAttribute((const void*)gemm_a256<0>,
            hipFuncAttributeMaxDynamicSharedMemorySize, 131072);
    (void)hipFuncSetAttribute((const void*)gemm_a256<2>,
            hipFuncAttributeMaxDynamicSharedMemorySize, 131072);
    (void)hipFuncSetAttribute((const void*)scores8,
            hipFuncAttributeMaxDynamicSharedMemorySize, 163840);
    (void)hipFuncSetAttribute((const void*)pv128,
            hipFuncAttributeMaxDynamicSharedMemorySize, 81920);
    (void)hipFuncSetAttribute((const void*)transpose_vwi,
            hipFuncAttributeMaxDynamicSharedMemorySize, 131072);

    // streaming converts
    convert_qkw<<<2048, 256, 0, stream>>>(q, k, wi, qb, kb, Wb);

    // 256x256 macro transposes (wide segments both directions)
    transpose_vwi<<<144, 512, 131072, stream>>>(v, wi, vT, Wt);

    // G = W @ W^T  (1024x1024, 32 blocks)
    gemm_a256<0><<<dim3(8, 4), 512, 131072, stream>>>(Wb, Wb, G, nullptr);

    // qG = q @ G   (8192x1024, 256 blocks = exactly 1 round)
    gemm_a256<0><<<dim3(8, 32), 512, 131072, stream>>>(qb, G, qG, nullptr);

    // scores: P = qG @ kb^T * 1/32; 144 causal 256x256 tiles, 8-phase engine
    scores8<<<dim3(8, 18), 512, 163840, stream>>>(qG, kb, P);

    softmax_rows<<<dim3(512, 4), 256, 0, stream>>>(P);

    // Y = attn @ v + qb  (bf16 residual)
    pv128<<<dim3(512), 256, 81920, stream>>>(P, vT, qb, Y);

    // out = Y @ W  (f32, 256 blocks = exactly 1 round)
    gemm_a256<2><<<dim3(8, 32), 512, 131072, stream>>>(Y, Wt, nullptr, out);
}

// Round 21
// 160.300 us; speedup vs baseline: 1.1867x; 1.1867x over previous
//
#include <hip/hip_runtime.h>
#include <hip/hip_bf16.h>

typedef __hip_bfloat16 bf16;
typedef short bf16x8 __attribute__((ext_vector_type(8)));
typedef float f32x4 __attribute__((ext_vector_type(4)));

#define HT 16384   // bf16 half-tile bytes: 128 rows x 64 cols

__device__ __forceinline__ void gload16(const void* g, void* l) {
    __builtin_amdgcn_global_load_lds(
        (const __attribute__((address_space(1))) void*)g,
        (__attribute__((address_space(3))) void*)l, 16, 0, 0);
}

// 512-thread staging of one 128x64 half-tile (2 gload16/thread)
__device__ __forceinline__ void stage_half(char* lds, const bf16* src, int ld,
                                           int rowbase, int k0, int slotIdx,
                                           int tid)
{
    char* dst = lds + (size_t)slotIdx * HT + tid * 16;
    const int sub = tid >> 3;
    const int cb  = ((tid & 7) ^ (sub & 7)) << 4;
    #pragma unroll
    for (int p = 0; p < 2; ++p) {
        const int row = p * 64 + sub;
        const char* g = (const char*)(src + (size_t)(rowbase + row) * ld + k0) + cb;
        gload16(g, dst + p * 8192);
    }
}

// 256-thread staging of one 128x64 half-tile (4 gload16/thread)
__device__ __forceinline__ void stage_q(char* lds, const bf16* src, int ld,
                                        int rowbase, int k0, int slotIdx,
                                        int tid)
{
    char* dst = lds + (size_t)slotIdx * HT + tid * 16;
    #pragma unroll
    for (int p = 0; p < 4; ++p) {
        const int s = p * 256 + tid;
        const int row = s >> 3;
        const int cb = ((s & 7) ^ (row & 7)) << 4;
        const char* g = (const char*)(src + (size_t)(rowbase + row) * ld + k0) + cb;
        gload16(g, dst + p * 4096);
    }
}

// read one MFMA A/B fragment (8 bf16 = 16B) with the read-side swizzle
__device__ __forceinline__ bf16x8 ldsfrag(const char* lds, int slotIdx,
                                          int row, int ks, int cb0)
{
    return *(const bf16x8*)(lds + (size_t)slotIdx * HT
                            + row * 128 + (cb0 ^ (ks << 6)));
}

__device__ __forceinline__ float bf2f(short s) {
    union { float f; unsigned u; } c;
    c.u = ((unsigned)(unsigned short)s) << 16;
    return c.f;
}

// ====== core 256x128 K=1024 loop body (8 waves 4Mx2N, 128 KiB LDS) ======
#define MF8(n0)                                                               \
    _Pragma("unroll") for (int m = 0; m < 4; ++m)                             \
    _Pragma("unroll") for (int dn = 0; dn < 2; ++dn)                          \
    _Pragma("unroll") for (int ks = 0; ks < 2; ++ks)                          \
        acc[m][(n0)+dn] = __builtin_amdgcn_mfma_f32_16x16x32_bf16(            \
            af[m][ks], bv[(n0)+dn][ks], acc[m][(n0)+dn], 0, 0, 0);

#define GEMM256_BODY(A_, lda_, B_, ldb_, brow_, bcol_)                        \
    f32x4 acc[4][4] = {};                                                     \
    bf16x8 af[4][2], bv[4][2];                                                \
    stage_half(lds, A_, lda_, brow_,       0, 0, tid);                        \
    stage_half(lds, A_, lda_, brow_ + 128, 0, 1, tid);                        \
    stage_half(lds, B_, ldb_, bcol_,       0, 6, tid);                        \
    stage_half(lds, A_, lda_, brow_,      64, 2, tid);                        \
    stage_half(lds, A_, lda_, brow_ + 128,64, 3, tid);                        \
    stage_half(lds, B_, ldb_, bcol_,     64, 7, tid);                         \
    asm volatile("s_waitcnt vmcnt(6)" ::: "memory");                          \
    __builtin_amdgcn_s_barrier();                                             \
    for (int t = 0; t < 16; ++t) {                                            \
        const int aslot = (t % 3) * 2 + hA;                                   \
        const int bslot = 6 + (t & 1);                                        \
        const int a2    = ((t + 2) % 3) * 2;                                  \
        const int k2    = min(t + 2, 15) << 6;                                \
        _Pragma("unroll") for (int m = 0; m < 4; ++m)                         \
        _Pragma("unroll") for (int ks = 0; ks < 2; ++ks)                      \
            af[m][ks] = ldsfrag(lds, aslot, rA + m * 16 + fr, ks, cb0);       \
        _Pragma("unroll") for (int n = 0; n < 4; ++n)                         \
        _Pragma("unroll") for (int ks = 0; ks < 2; ++ks)                      \
            bv[n][ks] = ldsfrag(lds, bslot, rB + n * 16 + fr, ks, cb0);       \
        stage_half(lds, A_, lda_, brow_,       k2, a2,     tid);              \
        stage_half(lds, A_, lda_, brow_ + 128, k2, a2 + 1, tid);              \
        __builtin_amdgcn_s_barrier();                                         \
        __builtin_amdgcn_s_setprio(1);                                        \
        MF8(0)                                                                \
        __builtin_amdgcn_s_setprio(0);                                        \
        __builtin_amdgcn_s_barrier();                                         \
        stage_half(lds, B_, ldb_, bcol_, k2, bslot, tid);                     \
        __builtin_amdgcn_s_barrier();                                         \
        __builtin_amdgcn_s_setprio(1);                                        \
        MF8(2)                                                                \
        __builtin_amdgcn_s_setprio(0);                                        \
        asm volatile("s_waitcnt vmcnt(6)" ::: "memory");                      \
        __builtin_amdgcn_s_barrier();                                         \
    }

// generic K=1024 GEMM: MODE 0: Cb = bf16(A@B^T).  MODE 2: Cf = f32(A@B^T).
template<int MODE>
__launch_bounds__(512, 2)
__global__ void gemm_a256(const bf16* __restrict__ A, const bf16* __restrict__ B,
                          bf16* __restrict__ Cb, float* __restrict__ Cf)
{
    extern __shared__ char lds[];
    const int gx = gridDim.x;
    const int nwg = gx * gridDim.y;
    const int chunk = nwg >> 3;
    const int orig = blockIdx.y * gx + blockIdx.x;
    const int wk2 = (orig & 7) * chunk + (orig >> 3);
    const int bi = wk2 / gx, bj = wk2 % gx;
    const int brow = bi * 256, bcol = bj * 128;

    const int tid  = threadIdx.x;
    const int lane = tid & 63;
    const int w    = tid >> 6;
    const int wm   = w >> 1, wn = w & 1;               // 4M x 2N, wave 64x64
    const int fr   = lane & 15, fq = lane >> 4;
    const int cb0  = ((fr & 7) ^ fq) << 4;
    const int hA   = wm >> 1;
    const int rA   = (wm & 1) * 64;
    const int rB   = wn * 64;

    GEMM256_BODY(A, 1024, B, 1024, brow, bcol)

    #pragma unroll
    for (int mf = 0; mf < 4; ++mf) {
        const int r0 = brow + wm * 64 + mf * 16 + fq * 4;
        #pragma unroll
        for (int nf = 0; nf < 4; ++nf) {
            const int c = bcol + wn * 64 + nf * 16 + fr;
            #pragma unroll
            for (int j = 0; j < 4; ++j) {
                if (MODE == 0)
                    Cb[(size_t)(r0 + j) * 1024 + c] =
                        __float2bfloat16(acc[mf][nf][j]);
                else
                    Cf[(size_t)(r0 + j) * 1024 + c] = acc[mf][nf][j];
            }
        }
    }
}

// ====== scores, 8-phase 256x256 template (m201 schedule; R13-proven) ======
__launch_bounds__(512, 1)
__global__ void scores8(const bf16* __restrict__ qG, const bf16* __restrict__ kb,
                        bf16* __restrict__ P)
{
    extern __shared__ char lds[];
    const int orig = blockIdx.y * 8 + blockIdx.x;     // grid (8,18) = 144
    const int wk2 = (orig & 7) * 18 + (orig >> 3);    // bijective, 18/XCD
    const int bz = wk2 / 36;
    const int j  = wk2 % 36;
    int bi = (int)((__fsqrt_rn(8.0f * j + 1.0f) - 1.0f) * 0.5f);
    while ((bi + 1) * (bi + 2) / 2 <= j) ++bi;
    while (bi * (bi + 1) / 2 > j) --bi;
    const int bj = j - bi * (bi + 1) / 2;             // bj <= bi
    const int brow = bi * 256, bcol = bj * 256;
    const bf16* A = qG + (size_t)bz * 2048 * 1024;
    const bf16* B = kb + (size_t)bz * 2048 * 1024;
    bf16* Cp = P + (size_t)bz * 2048 * 2048;

    const int tid  = threadIdx.x;
    const int lane = tid & 63;
    const int w    = tid >> 6;
    const int wm   = w >> 2;              // A half this wave owns (0..1)
    const int wn   = w & 3;               // B 64-col group (0..3)
    const int bh   = wn >> 1;             // B half slot
    const int rBl  = (wn & 1) * 64;       // local row base in B half
    const int fr   = lane & 15, fq = lane >> 4;
    const int cb0  = ((fr & 7) ^ fq) << 4;

    f32x4 acc[8][4] = {};
    bf16x8 af0[4][2], af1[4][2], bv0[2][2], bv1[2][2];

#define AS(t,h) ((((t) % 3) * 2) + (h))
#define BS(t,h) (6 + (((t) & 1) * 2) + (h))

    stage_half(lds, A, 1024, brow,       0, AS(0,0), tid);
    stage_half(lds, A, 1024, brow + 128, 0, AS(0,1), tid);
    stage_half(lds, B, 1024, bcol,       0, BS(0,0), tid);
    stage_half(lds, B, 1024, bcol + 128, 0, BS(0,1), tid);
    stage_half(lds, A, 1024, brow,      64, AS(1,0), tid);
    stage_half(lds, A, 1024, brow + 128,64, AS(1,1), tid);
    stage_half(lds, B, 1024, bcol,     64, BS(1,0), tid);
    asm volatile("s_waitcnt vmcnt(6)" ::: "memory");
    __builtin_amdgcn_s_barrier();

#define MFQ(MH, NH, AF, BV)                                                   \
    _Pragma("unroll") for (int m = 0; m < 4; ++m)                             \
    _Pragma("unroll") for (int n = 0; n < 2; ++n)                             \
    _Pragma("unroll") for (int ks = 0; ks < 2; ++ks)                          \
        acc[(MH)*4+m][(NH)*2+n] = __builtin_amdgcn_mfma_f32_16x16x32_bf16(    \
            AF[m][ks], BV[n][ks], acc[(MH)*4+m][(NH)*2+n], 0, 0, 0);

    for (int t = 0; t < 16; ++t) {
        const int kN  = min(t + 1, 15) << 6;
        const int kNN = min(t + 2, 15) << 6;
        const int as  = AS(t, wm);
        const int bs2 = BS(t, bh);

        // ph0: quadrant (0,0); stage B1(t+1)
        #pragma unroll
        for (int m = 0; m < 4; ++m)
            #pragma unroll
            for (int ks = 0; ks < 2; ++ks)
                af0[m][ks] = ldsfrag(lds, as, m * 16 + fr, ks, cb0);
        #pragma unroll
        for (int n = 0; n < 2; ++n)
            #pragma unroll
            for (int ks = 0; ks < 2; ++ks)
                bv0[n][ks] = ldsfrag(lds, bs2, rBl + n * 16 + fr, ks, cb0);
        stage_half(lds, B, 1024, bcol + 128, kN, BS(t + 1, 1), tid);
        __builtin_amdgcn_s_barrier();
        __builtin_amdgcn_s_setprio(1);
        MFQ(0, 0, af0, bv0)
        __builtin_amdgcn_s_setprio(0);
        __builtin_amdgcn_s_barrier();

        // ph1: quadrant (1,0); stage A0(t+2)
        #pragma unroll
        for (int m = 0; m < 4; ++m)
            #pragma unroll
            for (int ks = 0; ks < 2; ++ks)
                af1[m][ks] = ldsfrag(lds, as, 64 + m * 16 + fr, ks, cb0);
        stage_half(lds, A, 1024, brow, kNN, AS(t + 2, 0), tid);
        __builtin_amdgcn_s_barrier();
        __builtin_amdgcn_s_setprio(1);
        MFQ(1, 0, af1, bv0)
        __builtin_amdgcn_s_setprio(0);
        __builtin_amdgcn_s_barrier();

        // ph2: quadrant (1,1); stage A1(t+2)
        #pragma unroll
        for (int n = 0; n < 2; ++n)
            #pragma unroll
            for (int ks = 0; ks < 2; ++ks)
                bv1[n][ks] = ldsfrag(lds, bs2, rBl + 32 + n * 16 + fr, ks, cb0);
        stage_half(lds, A, 1024, brow + 128, kNN, AS(t + 2, 1), tid);
        __builtin_amdgcn_s_barrier();
        __builtin_amdgcn_s_setprio(1);
        MFQ(1, 1, af1, bv1)
        __builtin_amdgcn_s_setprio(0);
        __builtin_amdgcn_s_barrier();

        // ph3: quadrant (0,1); stage B0(t+2); counted vmcnt(6)
        stage_half(lds, B, 1024, bcol, kNN, BS(t + 2, 0), tid);
        __builtin_amdgcn_s_barrier();
        __builtin_amdgcn_s_setprio(1);
        MFQ(0, 1, af0, bv1)
        __builtin_amdgcn_s_setprio(0);
        asm volatile("s_waitcnt vmcnt(6)" ::: "memory");
        __builtin_amdgcn_s_barrier();
    }
#undef MFQ
#undef AS
#undef BS

    #pragma unroll
    for (int mf = 0; mf < 8; ++mf) {
        const int r0 = brow + wm * 128 + mf * 16 + fq * 4;
        #pragma unroll
        for (int nf = 0; nf < 4; ++nf) {
            const int c = bcol + wn * 64 + nf * 16 + fr;
            #pragma unroll
            for (int jj = 0; jj < 4; ++jj)
                Cp[(size_t)(r0 + jj) * 2048 + c] =
                    __float2bfloat16(acc[mf][nf][jj] * 0.03125f);
        }
    }
}

// ====== PV engine: 256 thr, 4 waves 2Mx2N, block 128x128, 80 KiB ======
__device__ __forceinline__ void tile128pv(char* lds, const bf16* A, const bf16* B,
                                          bf16* Cb, const bf16* Res,
                                          int lda, int ldb, int ldcb,
                                          int brow, int bcol, int NT, int tid)
{
    const int lane = tid & 63;
    const int w    = tid >> 6;
    const int wm   = w >> 1, wn = w & 1;
    const int fr   = lane & 15, fq = lane >> 4;
    const int cb0  = ((fr & 7) ^ fq) << 4;

    f32x4 acc[4][4] = {};
    bf16x8 af[4][2], bv[4][2];

    stage_q(lds, A, lda, brow, 0,  0, tid);
    stage_q(lds, B, ldb, bcol, 0,  3, tid);
    stage_q(lds, A, lda, brow, 64, 1, tid);
    stage_q(lds, B, ldb, bcol, 64, 4, tid);
    asm volatile("s_waitcnt vmcnt(8)" ::: "memory");
    __builtin_amdgcn_s_barrier();

    for (int t = 0; t < NT; ++t) {
        const int aslot = t % 3, bslot = 3 + (t & 1);
        const int k2 = min(t + 2, NT - 1) << 6;

        #pragma unroll
        for (int m = 0; m < 4; ++m)
            #pragma unroll
            for (int ks = 0; ks < 2; ++ks)
                af[m][ks] = ldsfrag(lds, aslot, wm * 64 + m * 16 + fr, ks, cb0);
        #pragma unroll
        for (int n = 0; n < 4; ++n)
            #pragma unroll
            for (int ks = 0; ks < 2; ++ks)
                bv[n][ks] = ldsfrag(lds, bslot, wn * 64 + n * 16 + fr, ks, cb0);
        stage_q(lds, A, lda, brow, k2, (t + 2) % 3, tid);
        __builtin_amdgcn_s_barrier();
        __builtin_amdgcn_s_setprio(1);
        #pragma unroll
        for (int m = 0; m < 4; ++m)
            #pragma unroll
            for (int n = 0; n < 2; ++n)
                #pragma unroll
                for (int ks = 0; ks < 2; ++ks)
                    acc[m][n] = __builtin_amdgcn_mfma_f32_16x16x32_bf16(
                        af[m][ks], bv[n][ks], acc[m][n], 0, 0, 0);
        __builtin_amdgcn_s_setprio(0);
        __builtin_amdgcn_s_barrier();

        stage_q(lds, B, ldb, bcol, k2, bslot, tid);
        __builtin_amdgcn_s_barrier();
        __builtin_amdgcn_s_setprio(1);
        #pragma unroll
        for (int m = 0; m < 4; ++m)
            #pragma unroll
            for (int n = 2; n < 4; ++n)
                #pragma unroll
                for (int ks = 0; ks < 2; ++ks)
                    acc[m][n] = __builtin_amdgcn_mfma_f32_16x16x32_bf16(
                        af[m][ks], bv[n][ks], acc[m][n], 0, 0, 0);
        __builtin_amdgcn_s_setprio(0);
        asm volatile("s_waitcnt vmcnt(8)" ::: "memory");
        __builtin_amdgcn_s_barrier();
    }

    #pragma unroll
    for (int mf = 0; mf < 4; ++mf) {
        const int r0 = brow + wm * 64 + mf * 16 + fq * 4;
        #pragma unroll
        for (int nf = 0; nf < 4; ++nf) {
            const int c = bcol + wn * 64 + nf * 16 + fr;
            #pragma unroll
            for (int j = 0; j < 4; ++j)
                Cb[(size_t)(r0 + j) * ldcb + c] = __float2bfloat16(
                    acc[mf][nf][j] +
                    __bfloat162float(Res[(size_t)(r0 + j) * ldcb + c]));
        }
    }
}

// PV: Y = attn@v + qb (bf16 residual). 512 balanced single tiles.
__launch_bounds__(256, 2)
__global__ void pv128(const bf16* __restrict__ P, const bf16* __restrict__ vT,
                      const bf16* __restrict__ qb, bf16* __restrict__ Y)
{
    extern __shared__ char lds[];
    const int x  = blockIdx.x;                // 0..511
    const int u  = x & 255;
    const int bs = u & 7;
    const int bj = (u >> 3) & 7;
    const int bz = u >> 6;
    const int bi = (x >> 8) ? (15 - bs) : bs;

    tile128pv(lds,
              P + (size_t)bz * 2048 * 2048,
              vT + (size_t)bz * 1024 * 2048,
              Y + (size_t)bz * 2048 * 1024,
              qb + (size_t)bz * 2048 * 1024,
              2048, 2048, 1024,
              bi * 128, bj * 128, 2 * (bi + 1), threadIdx.x);
}

// 64x64 f32->bf16 transpose tile via LDS (stride 66 breaks bank pattern).
// Load: float4/lane (256B per 16-lane row). Store: bf16x8/lane (16B/lane).
__device__ __forceinline__ void tr64(const float* __restrict__ src, int ldsrc,
                                     bf16* __restrict__ dst, int lddst,
                                     int r0, int c0, int tid, bf16* tl)
{
    #pragma unroll
    for (int p = 0; p < 4; ++p) {
        const int rr = p * 16 + (tid >> 4);
        const int cc = (tid & 15) * 4;
        float4 x = *(const float4*)(src + (size_t)(r0 + rr) * ldsrc + c0 + cc);
        bf16* o = tl + rr * 66 + cc;
        o[0] = __float2bfloat16(x.x);
        o[1] = __float2bfloat16(x.y);
        o[2] = __float2bfloat16(x.z);
        o[3] = __float2bfloat16(x.w);
    }
    __syncthreads();
    #pragma unroll
    for (int p = 0; p < 2; ++p) {
        const int crow = p * 32 + (tid >> 3);
        const int sc   = (tid & 7) * 8;
        union { short h[8]; bf16x8 v8; } o;
        #pragma unroll
        for (int j = 0; j < 8; ++j) {
            bf16 hh = tl[(sc + j) * 66 + crow];
            o.h[j] = *(short*)&hh;
        }
        *(bf16x8*)(dst + (size_t)(c0 + crow) * lddst + r0 + sc) = o.v8;
    }
}

// ====== prep: converts (q,k,wi -> bf16) + transposes (v -> vT, wi -> Wt) ====
__global__ void prep(const float* __restrict__ q, const float* __restrict__ k,
                     const float* __restrict__ wi, const float* __restrict__ v,
                     bf16* __restrict__ qb, bf16* __restrict__ kb,
                     bf16* __restrict__ Wb, bf16* __restrict__ vT,
                     bf16* __restrict__ Wt)
{
    __shared__ bf16 tl[64 * 66];
    const int b = blockIdx.x;
    const int tid = threadIdx.x;
    if (b < 2048) {                       // vT[z][d][s] = bf16(v[z][s][d])
        const int z = b >> 9, rem = b & 511;
        const int d0 = (rem >> 5) * 64, s0 = (rem & 31) * 64;
        tr64(v + (size_t)z * 2048 * 1024, 1024,
             vT + (size_t)z * 1024 * 2048, 2048, s0, d0, tid, tl);
    } else if (b < 2304) {                // Wt[n][k2] = bf16(wi[k2][n])
        const int t2 = b - 2048;
        const int n0 = (t2 & 15) * 64, k0 = (t2 >> 4) * 64;
        tr64(wi, 1024, Wt, 1024, k0, n0, tid, tl);
    } else {                              // converts q,k,wi -> qb,kb,Wb
        const int N8 = 8192 * 1024 / 8, W8 = 1024 * 1024 / 8;
        const int total = 2 * N8 + W8;
        const int nconv = gridDim.x - 2304;
        for (int i = (b - 2304) * 256 + tid; i < total; i += nconv * 256) {
            const float4* s;
            bf16* dst;
            int j;
            if (i < N8)          { s = (const float4*)q;  dst = qb; j = i; }
            else if (i < 2 * N8) { s = (const float4*)k;  dst = kb; j = i - N8; }
            else                 { s = (const float4*)wi; dst = Wb; j = i - 2 * N8; }
            float4 a = s[2 * j], bb = s[2 * j + 1];
            float vals[8] = {a.x, a.y, a.z, a.w, bb.x, bb.y, bb.z, bb.w};
            union { short h[8]; bf16x8 v8; } o;
            #pragma unroll
            for (int e = 0; e < 8; ++e) {
                bf16 hh = __float2bfloat16(vals[e]);
                o.h[e] = *(short*)&hh;
            }
            ((bf16x8*)dst)[j] = o.v8;
        }
    }
}

// wave-per-row causal softmax, zero-fill to 128-aligned boundary
__launch_bounds__(256)
__global__ void softmax_rows(bf16* __restrict__ P)
{
    const int wid = threadIdx.x >> 6, lane = threadIdx.x & 63;
    const int r = blockIdx.x * 4 + wid, b = blockIdx.y;
    bf16* row = P + ((size_t)b * 2048 + r) * 2048;
    const int nv  = r + 1;
    const int rup = (r & ~127) + 128;

    float vals[4][8];
    float m = -1e30f;
    #pragma unroll
    for (int c = 0; c < 4; ++c) {
        const int k0 = c * 512 + lane * 8;
        if (k0 < rup) {
            bf16x8 x = *(const bf16x8*)(row + k0);
            #pragma unroll
            for (int j = 0; j < 8; ++j) {
                float f = (k0 + j < nv) ? bf2f(x[j]) : -1e30f;
                vals[c][j] = f;
                m = fmaxf(m, f);
            }
        } else {
            #pragma unroll
            for (int j = 0; j < 8; ++j) vals[c][j] = -1e30f;
        }
    }
    #pragma unroll
    for (int o = 32; o; o >>= 1) m = fmaxf(m, __shfl_xor(m, o));

    float sum = 0.f;
    #pragma unroll
    for (int c = 0; c < 4; ++c)
        #pragma unroll
        for (int j = 0; j < 8; ++j) {
            float e = __expf(vals[c][j] - m);
            vals[c][j] = e;
            sum += e;
        }
    #pragma unroll
    for (int o = 32; o; o >>= 1) sum += __shfl_xor(sum, o);
    const float inv = 1.0f / sum;

    #pragma unroll
    for (int c = 0; c < 4; ++c) {
        const int k0 = c * 512 + lane * 8;
        if (k0 < rup) {
            union { short h[8]; bf16x8 v8; } o;
            #pragma unroll
            for (int j = 0; j < 8; ++j) {
                bf16 hh = __float2bfloat16(vals[c][j] * inv);
                o.h[j] = *(short*)&hh;
            }
            *(bf16x8*)(row + k0) = o.v8;
        }
    }
}

extern "C" void kernel_launch(void* const* d_in, const int* in_sizes, int n_in,
                              void* d_out, int out_size, void* d_ws, size_t ws_size,
                              hipStream_t stream)
{
    const float* v  = (const float*)d_in[0];
    const float* k  = (const float*)d_in[1];
    const float* q  = (const float*)d_in[2];
    const float* wi = (const float*)d_in[3];
    float* out = (float*)d_out;

    char* ws = (char*)d_ws;
    const size_t MB = 1u << 20;
    bf16* Wb = (bf16*)(ws);                 // [1024][1024] W row-major
    bf16* Wt = (bf16*)(ws + 2 * MB);        // [1024][1024] W^T
    bf16* G  = (bf16*)(ws + 4 * MB);        // [1024][1024] W@W^T
    bf16* qb = (bf16*)(ws + 6 * MB);        // [8192][1024]
    bf16* kb = (bf16*)(ws + 22 * MB);       // [8192][1024]
    bf16* vT = (bf16*)(ws + 38 * MB);       // [4][1024][2048]
    bf16* qG = (bf16*)(ws + 54 * MB);       // [8192][1024]
    bf16* Y  = (bf16*)(ws + 70 * MB);       // [8192][1024]  q + attn@v
    bf16* P  = (bf16*)(ws + 86 * MB);       // [4][2048][2048]

    (void)hipFuncSetAttribute((const void*)gemm_a256<0>,
            hipFuncAttributeMaxDynamicSharedMemorySize, 131072);
    (void)hipFuncSetAttribute((const void*)gemm_a256<2>,
            hipFuncAttributeMaxDynamicSharedMemorySize, 131072);
    (void)hipFuncSetAttribute((const void*)scores8,
            hipFuncAttributeMaxDynamicSharedMemorySize, 163840);
    (void)hipFuncSetAttribute((const void*)pv128,
            hipFuncAttributeMaxDynamicSharedMemorySize, 81920);

    // prep: all converts + transposes in one launch (coalesced transposes)
    prep<<<5376, 256, 0, stream>>>(q, k, wi, v, qb, kb, Wb, vT, Wt);

    // G = W @ W^T  (1024x1024, 32 blocks)
    gemm_a256<0><<<dim3(8, 4), 512, 131072, stream>>>(Wb, Wb, G, nullptr);

    // qG = q @ G   (8192x1024, 256 blocks = exactly 1 round)
    gemm_a256<0><<<dim3(8, 32), 512, 131072, stream>>>(qb, G, qG, nullptr);

    // scores: P = qG @ kb^T * 1/32; 144 causal 256x256 tiles, 8-phase engine
    scores8<<<dim3(8, 18), 512, 163840, stream>>>(qG, kb, P);

    softmax_rows<<<dim3(512, 4), 256, 0, stream>>>(P);

    // Y = attn @ v + qb  (bf16 residual)
    pv128<<<dim3(512), 256, 81920, stream>>>(P, vT, qb, Y);

    // out = Y @ W  (f32, 256 blocks = exactly 1 round)
    gemm_a256<2><<<dim3(8, 32), 512, 131072, stream>>>(Y, Wt, nullptr, out);
}